// Round 15
// baseline (36.877 us; speedup 1.0000x reference)
//
#include <hip/hip_runtime.h>
#include <hip/hip_fp16.h>

// PatchMMD via fused im2col + MFMA patch-GEMM (R15).
//   D(i,j,p,q) = ||patch_i(p,q) - patch_j(p,q)||^2  (3x3 VALID -> 62x62)
//   K = exp(-D/40.5);  out = offmean(Kxx) - 2*mean(Kxy) + offmean(Kyy)
//
// Identity: D = pre_i + pre_j - 2*<patch_i,patch_j>. Stack 128 images; the
// per-position 128x128 Gram matrix is a K=9 GEMM -> mfma_f32_16x16x16f16
// (K=16 >= 9), 8 diag + 28 strict-lower 16x16 tiles (symmetry); diagonal
// elems -> exp2(~0)=1, subtracted exactly at combine.
//
// R15 vs R14:
//  - PIN pa/pb in VGPRs (asm "+v" after the one LDS read): R13/R14 showed
//    VGPR_Count=40 -> compiler was re-reading pren from LDS ~180x per wave
//    inside the epilogue (DS-pipe serialization ~5us/CU).
//  - single launch: per-block partial stores + release threadfence + u32
//    ticket; last block acquires and runs the verbatim combine in-kernel.
//    (NOT R13's fp64 CAS storm - one u32 atomic per block, data via plain
//    stores.) Deterministic: the winner computes the same ordered sum.

typedef __attribute__((ext_vector_type(4))) _Float16 half4v;
typedef __attribute__((ext_vector_type(4))) float f32x4;

#define NPOS 3844        // 62*62
#define WSTR 26          // window n-stride in u16 (13 dwords, odd -> no conflicts)
#define RSTR 24          // record stride in u16 (48B: 16B-aligned, 2-way banks)
#define NBLK 992         // 62 * 16

#if __has_builtin(__builtin_amdgcn_exp2f)
#define EXP2F(v) __builtin_amdgcn_exp2f(v)
#else
#define EXP2F(v) __expf((v) * 0.69314718055994530942f)
#endif

// ---------------- DPP helpers (validated R4..R14) ----------------
template<int CTRL>
__device__ __forceinline__ float dpp0_f(float v) {
    int r = __builtin_amdgcn_update_dpp(0, __float_as_int(v), CTRL, 0xf, 0xf, true);
    return __int_as_float(r);
}
template<int CTRL, int RM>
__device__ __forceinline__ float dppm_f(float v) {
    int r = __builtin_amdgcn_update_dpp(0, __float_as_int(v), CTRL, RM, 0xf, true);
    return __int_as_float(r);
}
__device__ __forceinline__ float wave_reduce_f(float v) {
    v += dpp0_f<0x111>(v);            // row_shr:1
    v += dpp0_f<0x112>(v);            // row_shr:2
    v += dpp0_f<0x114>(v);            // row_shr:4
    v += dpp0_f<0x118>(v);            // row_shr:8  -> lane 15 of each row
    v += dppm_f<0x142, 0xa>(v);       // bcast15 into rows 1,3
    v += dppm_f<0x143, 0xc>(v);       // bcast31 into rows 2,3 -> lane 63 total
    return v;
}
__device__ __forceinline__ unsigned short f16bits(float f) {
    __half h = __float2half(f);                  // RNE
    return *reinterpret_cast<unsigned short*>(&h);
}
__device__ __forceinline__ float f16tof(unsigned short u) {
    __half h = *reinterpret_cast<__half*>(&u);
    return __half2float(h);
}

// ---------------- fused kernel (single launch) ----------------
__global__ __launch_bounds__(256, 4) void mmd_fused_kernel(
    const float* __restrict__ x, const float* __restrict__ y,
    float* __restrict__ part, unsigned int* __restrict__ gcnt,
    float* __restrict__ out)
{
    const int t = threadIdx.x, wid = t >> 6, lane = t & 63;
    const int p  = blockIdx.x >> 4;        // output row 0..61
    const int qg = blockIdx.x & 15;        // q-quad
    const int q  = qg * 4 + wid;           // this wave's position; valid iff < 62

    __shared__ unsigned short win[128 * WSTR];    // [n][u*8 + c] f16, c=0..7
    __shared__ unsigned short rec[4 * 128 * RSTR];// [ql][n][24] k=0..15 (>=9 zero)
    __shared__ float pren[4 * 128];               // [ql][n] NS * ||patch||^2
    __shared__ float wred[3][4];
    __shared__ double wd[3][4];
    __shared__ int is_last;

    const float NS   = -1.0f / (40.5f * 0.69314718055994530942f);  // exp2 scale
    const float M2NS = -2.0f * NS;

    // ---- A: stage 12-col window (cols 4qg..4qg+7, 2nd group clamped) ----
    {
        const int cg1 = (qg < 15) ? qg + 1 : 15;   // clamp feeds only q>=62 waves
        #pragma unroll
        for (int k = 0; k < 3; ++k) {
            int it = t + k * 256;
            int n = it / 6, rem = it % 6;
            int u = rem >> 1, cg = rem & 1;
            const float* img = (n < 64) ? (x + n * 4096) : (y + (n - 64) * 4096);
            float4 v = *reinterpret_cast<const float4*>(
                img + (p + u) * 64 + ((cg ? cg1 : qg) << 2));
            unsigned int d0 = f16bits(v.x) | ((unsigned)f16bits(v.y) << 16);
            unsigned int d1 = f16bits(v.z) | ((unsigned)f16bits(v.w) << 16);
            unsigned int* w32 = reinterpret_cast<unsigned int*>(
                &win[n * WSTR + u * 8 + cg * 4]);
            w32[0] = d0; w32[1] = d1;
        }
    }
    __syncthreads();

    // ---- B: build records + pre, all lanes busy; 2 records per thread ----
    #pragma unroll
    for (int k = 0; k < 2; ++k) {
        int rid = t + k * 256;
        int ql = rid >> 7, n = rid & 127;
        const unsigned short* wp = &win[n * WSTR + ql];
        unsigned short b[9];
        #pragma unroll
        for (int u = 0; u < 3; ++u) {
            b[u * 3 + 0] = wp[u * 8 + 0];
            b[u * 3 + 1] = wp[u * 8 + 1];
            b[u * 3 + 2] = wp[u * 8 + 2];
        }
        float pre = 0.f;
        #pragma unroll
        for (int e = 0; e < 9; ++e) {
            float fv = f16tof(b[e]);
            pre = fmaf(fv, fv, pre);
        }
        uint4 pk;
        pk.x = b[0] | ((unsigned)b[1] << 16);
        pk.y = b[2] | ((unsigned)b[3] << 16);
        pk.z = b[4] | ((unsigned)b[5] << 16);
        pk.w = b[6] | ((unsigned)b[7] << 16);
        uint4 pk2;
        pk2.x = (unsigned)b[8]; pk2.y = 0u; pk2.z = 0u; pk2.w = 0u;
        uint4* dst = reinterpret_cast<uint4*>(&rec[(size_t)rid * RSTR]);
        dst[0] = pk; dst[1] = pk2;     // bytes [0,32): k0..15; [32,48) unused
        pren[rid] = pre * NS;
    }
    __syncthreads();

    // ---- C: fragments + pre slices. 16x16x16 f16 lane layout:
    // row/col = lane&15, k = (lane>>4)*4 + e.  C/D: col=lane&15, row=kg*4+m.
    const int r = lane & 15, kg = lane >> 4;
    half4v frag[8];
    #pragma unroll
    for (int g = 0; g < 8; ++g)
        frag[g] = *reinterpret_cast<const half4v*>(
            &rec[(size_t)(wid * 128 + g * 16 + r) * RSTR + kg * 4]);

    float pa[8][4], pb[8];
    #pragma unroll
    for (int g = 0; g < 8; ++g) {
        const float* pp = &pren[wid * 128 + g * 16 + kg * 4];
        pa[g][0] = pp[0]; pa[g][1] = pp[1]; pa[g][2] = pp[2]; pa[g][3] = pp[3];
        pb[g] = pren[wid * 128 + g * 16 + r];
    }
    // PIN pa/pb into VGPRs: forbid LDS rematerialization in the epilogue
    // (R13/R14 VGPR_Count=40 proved the compiler was re-reading pren per use).
    #pragma unroll
    for (int g = 0; g < 8; ++g)
        asm volatile("" : "+v"(pa[g][0]), "+v"(pa[g][1]), "+v"(pa[g][2]),
                          "+v"(pa[g][3]), "+v"(pb[g]));

    const f32x4 zf = {0.f, 0.f, 0.f, 0.f};
    float ad0 = 0.f, ad1 = 0.f, as0 = 0.f, as1 = 0.f, ac0 = 0.f, ac1 = 0.f;

    // ---- D: diag tiles, streamed (i==j elems -> exp2(~0)=1, removed later)
    #pragma unroll
    for (int g = 0; g < 8; ++g) {
        f32x4 c4 = __builtin_amdgcn_mfma_f32_16x16x16f16(frag[g], frag[g], zf, 0, 0, 0);
        float e = 0.f;
        #pragma unroll
        for (int m = 0; m < 4; ++m)
            e += EXP2F(fmaf(c4[m], M2NS, pa[g][m] + pb[g]));
        if (g & 1) ad1 += e; else ad0 += e;
    }

    // ---- 28 strict-lower tiles: same-half weight 2 at combine, cross 1 ----
    #pragma unroll
    for (int ti = 1; ti < 8; ++ti)
        #pragma unroll
        for (int tj = 0; tj < ti; ++tj) {
            f32x4 c4 = __builtin_amdgcn_mfma_f32_16x16x16f16(frag[ti], frag[tj], zf, 0, 0, 0);
            float e = 0.f;
            #pragma unroll
            for (int m = 0; m < 4; ++m)
                e += EXP2F(fmaf(c4[m], M2NS, pa[ti][m] + pb[tj]));
            if (ti >= 4 && tj < 4) { if (tj & 1) ac1 += e; else ac0 += e; }
            else                   { if (tj & 1) as1 += e; else as0 += e; }
        }

    float acc_diag  = wave_reduce_f(ad0 + ad1);
    float acc_same  = wave_reduce_f(as0 + as1);
    float acc_cross = wave_reduce_f(ac0 + ac1);
    if (lane == 63) {
        const bool valid = (q < 62);
        wred[0][wid] = valid ? acc_diag  : 0.f;
        wred[1][wid] = valid ? acc_same  : 0.f;
        wred[2][wid] = valid ? acc_cross : 0.f;
    }
    __syncthreads();

    // ---- E: per-block partial stores + release fence + u32 ticket ----
    if (t == 0) {
        #pragma unroll
        for (int c = 0; c < 3; ++c)
            part[c * NBLK + blockIdx.x] =
                (wred[c][0] + wred[c][1]) + (wred[c][2] + wred[c][3]);
        __threadfence();                           // release: partials visible
        unsigned int tick = atomicAdd(gcnt, 1u);
        is_last = (tick == NBLK - 1) ? 1 : 0;
    }
    __syncthreads();

    // ---- F: last block runs the (verbatim R14) fp64 combine in-kernel ----
    if (is_last) {
        __threadfence();                           // acquire: see all partials
        double sd = 0.0, ss = 0.0, sc = 0.0;
        #pragma unroll
        for (int k = 0; k < 4; ++k) {
            int e = t + k * 256;
            if (e < NBLK) {
                sd += (double)part[e];
                ss += (double)part[NBLK + e];
                sc += (double)part[2 * NBLK + e];
            }
        }
        #pragma unroll
        for (int off = 32; off > 0; off >>= 1) {
            sd += __shfl_xor(sd, off);
            ss += __shfl_xor(ss, off);
            sc += __shfl_xor(sc, off);
        }
        if (lane == 0) { wd[0][wid] = sd; wd[1][wid] = ss; wd[2][wid] = sc; }
        __syncthreads();
        if (t == 0) {
            double Sd = wd[0][0] + wd[0][1] + wd[0][2] + wd[0][3];
            double Ss = wd[1][0] + wd[1][1] + wd[1][2] + wd[1][3];
            double Sc = wd[2][0] + wd[2][1] + wd[2][2] + wd[2][3];
            // xx+yy off-diag ordered sums: diag tiles (minus exact-1 diagonal)
            // count each ordered pair once; lower same-half tiles count twice.
            double S_off = (Sd - 128.0 * (double)NPOS) + 2.0 * Ss;
            const double cnt_off = 64.0 * 63.0 * 62.0 * 62.0;  // N*(N-1)*h*w
            const double cnt_all = 64.0 * 64.0 * 62.0 * 62.0;
            out[0] = (float)(S_off / cnt_off - 2.0 * Sc / cnt_all);
        }
    }
}

// ---------------- launch ----------------
extern "C" void kernel_launch(void* const* d_in, const int* in_sizes, int n_in,
                              void* d_out, int out_size, void* d_ws, size_t ws_size,
                              hipStream_t stream) {
    const float* x = (const float*)d_in[0];
    const float* y = (const float*)d_in[1];
    float* out  = (float*)d_out;
    float* part = (float*)d_ws;                          // 3*NBLK floats
    unsigned int* gcnt = (unsigned int*)((char*)d_ws + 3 * NBLK * 4);

    (void)hipMemsetAsync(gcnt, 0, 4, stream);            // zero ticket (graph-legal)
    mmd_fused_kernel<<<NBLK, 256, 0, stream>>>(x, y, part, gcnt, out);
}

// Round 17
// 17.117 us; speedup vs baseline: 2.1544x; 2.1544x over previous
//
#include <hip/hip_runtime.h>
#include <hip/hip_fp16.h>

// PatchMMD via fused im2col + MFMA patch-GEMM (R17).
//   D(i,j,p,q) = ||patch_i(p,q) - patch_j(p,q)||^2  (3x3 VALID -> 62x62)
//   K = exp(-D/40.5);  out = offmean(Kxx) - 2*mean(Kxy) + offmean(Kyy)
//
// Identity: D = pre_i + pre_j - 2*<patch_i,patch_j>. Stack 128 images; the
// per-position 128x128 Gram matrix is a K=9 GEMM -> mfma_f32_16x16x16f16
// (K=16 >= 9), 8 diag + 28 strict-lower 16x16 tiles (symmetry); diagonal
// elems -> exp2(~0)=1, subtracted exactly at combine.
//
// R17 = R14 (known-pass, 17.3us) + ONE change: RSTR 24 -> 20 u16 (40B).
//   - ALL kg slices read LDS uniformly (kg=3 reads stored zeros) - NO
//     divergent ds_read (R16's exec-masked read + its post-timing flake
//     is the suspect construct; removed).
//   - 40B records: 8B-aligned uint2 stores/b64 reads; read banks
//     10*r mod 32 -> 16 distinct, conflict-free.
//   - LDS 33.4 -> 29.2 KB: 4 -> 5 blocks/CU (+25% resident waves).

typedef __attribute__((ext_vector_type(4))) _Float16 half4v;
typedef __attribute__((ext_vector_type(4))) float f32x4;

#define NPOS 3844        // 62*62
#define WSTR 26          // window n-stride in u16 (13 dwords, odd -> no conflicts)
#define RSTR 20          // record stride in u16 (40B: 8B-aligned, 16-bank pattern)
#define NBLK 992         // 62 * 16

#if __has_builtin(__builtin_amdgcn_exp2f)
#define EXP2F(v) __builtin_amdgcn_exp2f(v)
#else
#define EXP2F(v) __expf((v) * 0.69314718055994530942f)
#endif

// ---------------- DPP helpers (validated R4..R14) ----------------
template<int CTRL>
__device__ __forceinline__ float dpp0_f(float v) {
    int r = __builtin_amdgcn_update_dpp(0, __float_as_int(v), CTRL, 0xf, 0xf, true);
    return __int_as_float(r);
}
template<int CTRL, int RM>
__device__ __forceinline__ float dppm_f(float v) {
    int r = __builtin_amdgcn_update_dpp(0, __float_as_int(v), CTRL, RM, 0xf, true);
    return __int_as_float(r);
}
__device__ __forceinline__ float wave_reduce_f(float v) {
    v += dpp0_f<0x111>(v);            // row_shr:1
    v += dpp0_f<0x112>(v);            // row_shr:2
    v += dpp0_f<0x114>(v);            // row_shr:4
    v += dpp0_f<0x118>(v);            // row_shr:8  -> lane 15 of each row
    v += dppm_f<0x142, 0xa>(v);       // bcast15 into rows 1,3
    v += dppm_f<0x143, 0xc>(v);       // bcast31 into rows 2,3 -> lane 63 total
    return v;
}
__device__ __forceinline__ unsigned short f16bits(float f) {
    __half h = __float2half(f);                  // RNE
    return *reinterpret_cast<unsigned short*>(&h);
}
__device__ __forceinline__ float f16tof(unsigned short u) {
    __half h = *reinterpret_cast<__half*>(&u);
    return __half2float(h);
}

// ---------------- fused kernel ----------------
__global__ __launch_bounds__(256, 4) void mmd_fused_kernel(
    const float* __restrict__ x, const float* __restrict__ y,
    float* __restrict__ part)
{
    const int t = threadIdx.x, wid = t >> 6, lane = t & 63;
    const int p  = blockIdx.x >> 4;        // output row 0..61
    const int qg = blockIdx.x & 15;        // q-quad
    const int q  = qg * 4 + wid;           // this wave's position; valid iff < 62

    __shared__ unsigned short win[128 * WSTR];    // [n][u*8 + c] f16, c=0..7
    __shared__ unsigned short rec[4 * 128 * RSTR];// [ql][n][20] k=0..15 (>=9 zero)
    __shared__ float pren[4 * 128];               // [ql][n] NS * ||patch||^2
    __shared__ float wred[3][4];

    const float NS   = -1.0f / (40.5f * 0.69314718055994530942f);  // exp2 scale
    const float M2NS = -2.0f * NS;

    // ---- A: stage 12-col window (cols 4qg..4qg+7, 2nd group clamped) ----
    {
        const int cg1 = (qg < 15) ? qg + 1 : 15;   // clamp feeds only q>=62 waves
        #pragma unroll
        for (int k = 0; k < 3; ++k) {
            int it = t + k * 256;
            int n = it / 6, rem = it % 6;
            int u = rem >> 1, cg = rem & 1;
            const float* img = (n < 64) ? (x + n * 4096) : (y + (n - 64) * 4096);
            float4 v = *reinterpret_cast<const float4*>(
                img + (p + u) * 64 + ((cg ? cg1 : qg) << 2));
            unsigned int d0 = f16bits(v.x) | ((unsigned)f16bits(v.y) << 16);
            unsigned int d1 = f16bits(v.z) | ((unsigned)f16bits(v.w) << 16);
            unsigned int* w32 = reinterpret_cast<unsigned int*>(
                &win[n * WSTR + u * 8 + cg * 4]);
            w32[0] = d0; w32[1] = d1;
        }
    }
    __syncthreads();

    // ---- B: build records + pre, all lanes busy; 2 records per thread ----
    #pragma unroll
    for (int k = 0; k < 2; ++k) {
        int rid = t + k * 256;
        int ql = rid >> 7, n = rid & 127;
        const unsigned short* wp = &win[n * WSTR + ql];
        unsigned short b[9];
        #pragma unroll
        for (int u = 0; u < 3; ++u) {
            b[u * 3 + 0] = wp[u * 8 + 0];
            b[u * 3 + 1] = wp[u * 8 + 1];
            b[u * 3 + 2] = wp[u * 8 + 2];
        }
        float pre = 0.f;
        #pragma unroll
        for (int e = 0; e < 9; ++e) {
            float fv = f16tof(b[e]);
            pre = fmaf(fv, fv, pre);
        }
        unsigned short* dp = &rec[(size_t)rid * RSTR];
        uint2 s0, s1, s2, s3;
        s0.x = b[0] | ((unsigned)b[1] << 16);
        s0.y = b[2] | ((unsigned)b[3] << 16);
        s1.x = b[4] | ((unsigned)b[5] << 16);
        s1.y = b[6] | ((unsigned)b[7] << 16);
        s2.x = (unsigned)b[8]; s2.y = 0u;
        s3.x = 0u;             s3.y = 0u;
        *reinterpret_cast<uint2*>(dp)      = s0;   // k0..3
        *reinterpret_cast<uint2*>(dp + 4)  = s1;   // k4..7
        *reinterpret_cast<uint2*>(dp + 8)  = s2;   // k8,0,0,0
        *reinterpret_cast<uint2*>(dp + 12) = s3;   // k12..15 = 0 (kg=3 slice)
        pren[rid] = pre * NS;
    }
    __syncthreads();

    // ---- C: fragments + pre slices. 16x16x16 f16 lane layout:
    // row/col = lane&15, k = (lane>>4)*4 + e.  C/D: col=lane&15, row=kg*4+m.
    const int r = lane & 15, kg = lane >> 4;
    half4v frag[8];
    #pragma unroll
    for (int g = 0; g < 8; ++g)
        frag[g] = *reinterpret_cast<const half4v*>(
            &rec[(size_t)(wid * 128 + g * 16 + r) * RSTR + kg * 4]);

    float pa[8][4], pb[8];
    #pragma unroll
    for (int g = 0; g < 8; ++g) {
        const float* pp = &pren[wid * 128 + g * 16 + kg * 4];
        pa[g][0] = pp[0]; pa[g][1] = pp[1]; pa[g][2] = pp[2]; pa[g][3] = pp[3];
        pb[g] = pren[wid * 128 + g * 16 + r];
    }

    const f32x4 zf = {0.f, 0.f, 0.f, 0.f};
    float ad0 = 0.f, ad1 = 0.f, as0 = 0.f, as1 = 0.f, ac0 = 0.f, ac1 = 0.f;

    // ---- D: diag tiles, streamed (i==j elems -> exp2(~0)=1, removed later)
    #pragma unroll
    for (int g = 0; g < 8; ++g) {
        f32x4 c4 = __builtin_amdgcn_mfma_f32_16x16x16f16(frag[g], frag[g], zf, 0, 0, 0);
        float e = 0.f;
        #pragma unroll
        for (int m = 0; m < 4; ++m)
            e += EXP2F(fmaf(c4[m], M2NS, pa[g][m] + pb[g]));
        if (g & 1) ad1 += e; else ad0 += e;
    }

    // ---- 28 strict-lower tiles: same-half weight 2 at combine, cross 1 ----
    #pragma unroll
    for (int ti = 1; ti < 8; ++ti)
        #pragma unroll
        for (int tj = 0; tj < ti; ++tj) {
            f32x4 c4 = __builtin_amdgcn_mfma_f32_16x16x16f16(frag[ti], frag[tj], zf, 0, 0, 0);
            float e = 0.f;
            #pragma unroll
            for (int m = 0; m < 4; ++m)
                e += EXP2F(fmaf(c4[m], M2NS, pa[ti][m] + pb[tj]));
            if (ti >= 4 && tj < 4) { if (tj & 1) ac1 += e; else ac0 += e; }
            else                   { if (tj & 1) as1 += e; else as0 += e; }
        }

    float acc_diag  = wave_reduce_f(ad0 + ad1);
    float acc_same  = wave_reduce_f(as0 + as1);
    float acc_cross = wave_reduce_f(ac0 + ac1);
    if (lane == 63) {
        const bool valid = (q < 62);
        wred[0][wid] = valid ? acc_diag  : 0.f;
        wred[1][wid] = valid ? acc_same  : 0.f;
        wred[2][wid] = valid ? acc_cross : 0.f;
    }
    __syncthreads();
    if (t == 0) {
        #pragma unroll
        for (int c = 0; c < 3; ++c)
            part[c * NBLK + blockIdx.x] =
                (wred[c][0] + wred[c][1]) + (wred[c][2] + wred[c][3]);
    }
}

// ---------------- fp64 combine ----------------
__global__ __launch_bounds__(256) void mmd_final_kernel(
    const float* __restrict__ part, float* __restrict__ out)
{
    const int t = threadIdx.x;
    double sd = 0.0, ss = 0.0, sc = 0.0;
    #pragma unroll
    for (int k = 0; k < 4; ++k) {
        int e = t + k * 256;
        if (e < NBLK) {
            sd += (double)part[e];
            ss += (double)part[NBLK + e];
            sc += (double)part[2 * NBLK + e];
        }
    }
    #pragma unroll
    for (int off = 32; off > 0; off >>= 1) {
        sd += __shfl_xor(sd, off);
        ss += __shfl_xor(ss, off);
        sc += __shfl_xor(sc, off);
    }
    __shared__ double w[3][4];
    const int lane = t & 63, wd = t >> 6;
    if (lane == 0) { w[0][wd] = sd; w[1][wd] = ss; w[2][wd] = sc; }
    __syncthreads();
    if (t == 0) {
        double Sd = w[0][0] + w[0][1] + w[0][2] + w[0][3];
        double Ss = w[1][0] + w[1][1] + w[1][2] + w[1][3];
        double Sc = w[2][0] + w[2][1] + w[2][2] + w[2][3];
        // xx+yy off-diag ordered sums: diag tiles (minus exact-1 diagonal)
        // count each ordered pair once; lower same-half tiles count twice.
        double S_off = (Sd - 128.0 * (double)NPOS) + 2.0 * Ss;
        const double cnt_off = 64.0 * 63.0 * 62.0 * 62.0;   // per-set N*(N-1)*h*w
        const double cnt_all = 64.0 * 64.0 * 62.0 * 62.0;
        out[0] = (float)(S_off / cnt_off - 2.0 * Sc / cnt_all);
    }
}

// ---------------- launch ----------------
extern "C" void kernel_launch(void* const* d_in, const int* in_sizes, int n_in,
                              void* d_out, int out_size, void* d_ws, size_t ws_size,
                              hipStream_t stream) {
    const float* x = (const float*)d_in[0];
    const float* y = (const float*)d_in[1];
    float* out  = (float*)d_out;
    float* part = (float*)d_ws;   // 3 * 992 floats = 11.6 KiB

    mmd_fused_kernel<<<NBLK, 256, 0, stream>>>(x, y, part);
    mmd_final_kernel<<<1, 256, 0, stream>>>(part, out);
}

// Round 18
// 16.352 us; speedup vs baseline: 2.2553x; 1.0468x over previous
//
#include <hip/hip_runtime.h>
#include <hip/hip_fp16.h>

// PatchMMD via fused im2col + MFMA patch-GEMM (R18).
//   D(i,j,p,q) = ||patch_i(p,q) - patch_j(p,q)||^2  (3x3 VALID -> 62x62)
//   K = exp(-D/40.5);  out = offmean(Kxx) - 2*mean(Kxy) + offmean(Kyy)
//
// Identity: D = pre_i + pre_j - 2*<patch_i,patch_j>. Stack 128 images; the
// per-position 128x128 Gram matrix is a K=9 GEMM -> mfma_f32_16x16x16f16
// (K=16 >= 9), 8 diag + 28 strict-lower 16x16 tiles (symmetry); diagonal
// elems -> exp2(~0)=1, subtracted exactly at combine.
//
// R18 = R17 (pass, 17.1us) + ONE logical change: slim final reduce.
//   Fold combine weights into each block's single fp32 partial:
//     part[bid] = (sd + 2*ss)*w_off - 2*sc*w_all        (fp64 -> fp32)
//   Final kernel: one coalesced 992-float load over 1024 threads + reduce,
//   then subtract the exact global correction 128*NPOS*w_off once.
//   Error budget ~1e-9 abs (threshold 3.6e-6). Fused kernel otherwise
//   byte-identical to R17. This isolates the tail cost: if dur is
//   unchanged, the fused kernel itself is ~15us and R19 attacks its stalls.

typedef __attribute__((ext_vector_type(4))) _Float16 half4v;
typedef __attribute__((ext_vector_type(4))) float f32x4;

#define NPOS 3844        // 62*62
#define WSTR 26          // window n-stride in u16 (13 dwords, odd -> no conflicts)
#define RSTR 20          // record stride in u16 (40B: 8B-aligned, 16-bank pattern)
#define NBLK 992         // 62 * 16

#define W_OFF (1.0 / (64.0 * 63.0 * 62.0 * 62.0))   // per-set N*(N-1)*h*w
#define W_ALL (1.0 / (64.0 * 64.0 * 62.0 * 62.0))   // N*N*h*w

#if __has_builtin(__builtin_amdgcn_exp2f)
#define EXP2F(v) __builtin_amdgcn_exp2f(v)
#else
#define EXP2F(v) __expf((v) * 0.69314718055994530942f)
#endif

// ---------------- DPP helpers (validated R4..R17) ----------------
template<int CTRL>
__device__ __forceinline__ float dpp0_f(float v) {
    int r = __builtin_amdgcn_update_dpp(0, __float_as_int(v), CTRL, 0xf, 0xf, true);
    return __int_as_float(r);
}
template<int CTRL, int RM>
__device__ __forceinline__ float dppm_f(float v) {
    int r = __builtin_amdgcn_update_dpp(0, __float_as_int(v), CTRL, RM, 0xf, true);
    return __int_as_float(r);
}
__device__ __forceinline__ float wave_reduce_f(float v) {
    v += dpp0_f<0x111>(v);            // row_shr:1
    v += dpp0_f<0x112>(v);            // row_shr:2
    v += dpp0_f<0x114>(v);            // row_shr:4
    v += dpp0_f<0x118>(v);            // row_shr:8  -> lane 15 of each row
    v += dppm_f<0x142, 0xa>(v);       // bcast15 into rows 1,3
    v += dppm_f<0x143, 0xc>(v);       // bcast31 into rows 2,3 -> lane 63 total
    return v;
}
__device__ __forceinline__ unsigned short f16bits(float f) {
    __half h = __float2half(f);                  // RNE
    return *reinterpret_cast<unsigned short*>(&h);
}
__device__ __forceinline__ float f16tof(unsigned short u) {
    __half h = *reinterpret_cast<__half*>(&u);
    return __half2float(h);
}

// ---------------- fused kernel ----------------
__global__ __launch_bounds__(256, 4) void mmd_fused_kernel(
    const float* __restrict__ x, const float* __restrict__ y,
    float* __restrict__ part)
{
    const int t = threadIdx.x, wid = t >> 6, lane = t & 63;
    const int p  = blockIdx.x >> 4;        // output row 0..61
    const int qg = blockIdx.x & 15;        // q-quad
    const int q  = qg * 4 + wid;           // this wave's position; valid iff < 62

    __shared__ unsigned short win[128 * WSTR];    // [n][u*8 + c] f16, c=0..7
    __shared__ unsigned short rec[4 * 128 * RSTR];// [ql][n][20] k=0..15 (>=9 zero)
    __shared__ float pren[4 * 128];               // [ql][n] NS * ||patch||^2
    __shared__ float wred[3][4];

    const float NS   = -1.0f / (40.5f * 0.69314718055994530942f);  // exp2 scale
    const float M2NS = -2.0f * NS;

    // ---- A: stage 12-col window (cols 4qg..4qg+7, 2nd group clamped) ----
    {
        const int cg1 = (qg < 15) ? qg + 1 : 15;   // clamp feeds only q>=62 waves
        #pragma unroll
        for (int k = 0; k < 3; ++k) {
            int it = t + k * 256;
            int n = it / 6, rem = it % 6;
            int u = rem >> 1, cg = rem & 1;
            const float* img = (n < 64) ? (x + n * 4096) : (y + (n - 64) * 4096);
            float4 v = *reinterpret_cast<const float4*>(
                img + (p + u) * 64 + ((cg ? cg1 : qg) << 2));
            unsigned int d0 = f16bits(v.x) | ((unsigned)f16bits(v.y) << 16);
            unsigned int d1 = f16bits(v.z) | ((unsigned)f16bits(v.w) << 16);
            unsigned int* w32 = reinterpret_cast<unsigned int*>(
                &win[n * WSTR + u * 8 + cg * 4]);
            w32[0] = d0; w32[1] = d1;
        }
    }
    __syncthreads();

    // ---- B: build records + pre, all lanes busy; 2 records per thread ----
    #pragma unroll
    for (int k = 0; k < 2; ++k) {
        int rid = t + k * 256;
        int ql = rid >> 7, n = rid & 127;
        const unsigned short* wp = &win[n * WSTR + ql];
        unsigned short b[9];
        #pragma unroll
        for (int u = 0; u < 3; ++u) {
            b[u * 3 + 0] = wp[u * 8 + 0];
            b[u * 3 + 1] = wp[u * 8 + 1];
            b[u * 3 + 2] = wp[u * 8 + 2];
        }
        float pre = 0.f;
        #pragma unroll
        for (int e = 0; e < 9; ++e) {
            float fv = f16tof(b[e]);
            pre = fmaf(fv, fv, pre);
        }
        unsigned short* dp = &rec[(size_t)rid * RSTR];
        uint2 s0, s1, s2, s3;
        s0.x = b[0] | ((unsigned)b[1] << 16);
        s0.y = b[2] | ((unsigned)b[3] << 16);
        s1.x = b[4] | ((unsigned)b[5] << 16);
        s1.y = b[6] | ((unsigned)b[7] << 16);
        s2.x = (unsigned)b[8]; s2.y = 0u;
        s3.x = 0u;             s3.y = 0u;
        *reinterpret_cast<uint2*>(dp)      = s0;   // k0..3
        *reinterpret_cast<uint2*>(dp + 4)  = s1;   // k4..7
        *reinterpret_cast<uint2*>(dp + 8)  = s2;   // k8,0,0,0
        *reinterpret_cast<uint2*>(dp + 12) = s3;   // k12..15 = 0 (kg=3 slice)
        pren[rid] = pre * NS;
    }
    __syncthreads();

    // ---- C: fragments + pre slices. 16x16x16 f16 lane layout:
    // row/col = lane&15, k = (lane>>4)*4 + e.  C/D: col=lane&15, row=kg*4+m.
    const int r = lane & 15, kg = lane >> 4;
    half4v frag[8];
    #pragma unroll
    for (int g = 0; g < 8; ++g)
        frag[g] = *reinterpret_cast<const half4v*>(
            &rec[(size_t)(wid * 128 + g * 16 + r) * RSTR + kg * 4]);

    float pa[8][4], pb[8];
    #pragma unroll
    for (int g = 0; g < 8; ++g) {
        const float* pp = &pren[wid * 128 + g * 16 + kg * 4];
        pa[g][0] = pp[0]; pa[g][1] = pp[1]; pa[g][2] = pp[2]; pa[g][3] = pp[3];
        pb[g] = pren[wid * 128 + g * 16 + r];
    }

    const f32x4 zf = {0.f, 0.f, 0.f, 0.f};
    float ad0 = 0.f, ad1 = 0.f, as0 = 0.f, as1 = 0.f, ac0 = 0.f, ac1 = 0.f;

    // ---- D: diag tiles, streamed (i==j elems -> exp2(~0)=1, removed later)
    #pragma unroll
    for (int g = 0; g < 8; ++g) {
        f32x4 c4 = __builtin_amdgcn_mfma_f32_16x16x16f16(frag[g], frag[g], zf, 0, 0, 0);
        float e = 0.f;
        #pragma unroll
        for (int m = 0; m < 4; ++m)
            e += EXP2F(fmaf(c4[m], M2NS, pa[g][m] + pb[g]));
        if (g & 1) ad1 += e; else ad0 += e;
    }

    // ---- 28 strict-lower tiles: same-half weight 2 at combine, cross 1 ----
    #pragma unroll
    for (int ti = 1; ti < 8; ++ti)
        #pragma unroll
        for (int tj = 0; tj < ti; ++tj) {
            f32x4 c4 = __builtin_amdgcn_mfma_f32_16x16x16f16(frag[ti], frag[tj], zf, 0, 0, 0);
            float e = 0.f;
            #pragma unroll
            for (int m = 0; m < 4; ++m)
                e += EXP2F(fmaf(c4[m], M2NS, pa[ti][m] + pb[tj]));
            if (ti >= 4 && tj < 4) { if (tj & 1) ac1 += e; else ac0 += e; }
            else                   { if (tj & 1) as1 += e; else as0 += e; }
        }

    float acc_diag  = wave_reduce_f(ad0 + ad1);
    float acc_same  = wave_reduce_f(as0 + as1);
    float acc_cross = wave_reduce_f(ac0 + ac1);
    if (lane == 63) {
        const bool valid = (q < 62);
        wred[0][wid] = valid ? acc_diag  : 0.f;
        wred[1][wid] = valid ? acc_same  : 0.f;
        wred[2][wid] = valid ? acc_cross : 0.f;
    }
    __syncthreads();
    if (t == 0) {
        // fold combine weights into ONE fp32 partial per block:
        //   val = (sd + 2*ss)*w_off - 2*sc*w_all   (global -128*NPOS*w_off
        //   correction applied once in the final kernel)
        double sd = (double)((wred[0][0] + wred[0][1]) + (wred[0][2] + wred[0][3]));
        double ss = (double)((wred[1][0] + wred[1][1]) + (wred[1][2] + wred[1][3]));
        double sc = (double)((wred[2][0] + wred[2][1]) + (wred[2][2] + wred[2][3]));
        part[blockIdx.x] = (float)((sd + 2.0 * ss) * W_OFF - 2.0 * sc * W_ALL);
    }
}

// ---------------- slim fp64 combine: one coalesced load + reduce ----------------
__global__ __launch_bounds__(1024) void mmd_final_kernel(
    const float* __restrict__ part, float* __restrict__ out)
{
    const int t = threadIdx.x;
    double v = (t < NBLK) ? (double)part[t] : 0.0;
    #pragma unroll
    for (int off = 32; off > 0; off >>= 1)
        v += __shfl_xor(v, off);
    __shared__ double w[16];
    const int lane = t & 63, wd = t >> 6;
    if (lane == 0) w[wd] = v;
    __syncthreads();
    if (t == 0) {
        double S = 0.0;
        #pragma unroll
        for (int k = 0; k < 16; ++k) S += w[k];
        out[0] = (float)(S - 128.0 * (double)NPOS * W_OFF);  // remove exact-1 diagonal
    }
}

// ---------------- launch ----------------
extern "C" void kernel_launch(void* const* d_in, const int* in_sizes, int n_in,
                              void* d_out, int out_size, void* d_ws, size_t ws_size,
                              hipStream_t stream) {
    const float* x = (const float*)d_in[0];
    const float* y = (const float*)d_in[1];
    float* out  = (float*)d_out;
    float* part = (float*)d_ws;   // 992 floats = 3.9 KiB

    mmd_fused_kernel<<<NBLK, 256, 0, stream>>>(x, y, part);
    mmd_final_kernel<<<1, 1024, 0, stream>>>(part, out);
}